// Round 7
// baseline (1499.012 us; speedup 1.0000x reference)
//
#include <hip/hip_runtime.h>

// Billeh column GLIF forward — persistent cooperative kernel, fence-free
// barriers. One thread owns one neuron; all neuron state in registers for
// the whole run. Cross-block data goes through the L3 coherence point only:
// rec_in via device-scope atomicAdd / agent-scope loads+stores, spike mask
// via agent-scope stores, staged into LDS per step for the synapse scan.
// Barrier = __syncthreads (drains vmcnt) + relaxed agent counter + poll.
// NO __threadfence anywhere (R4's 28us/sync was the L2 writeback it emits).

constexpr int RR   = 4;
constexpr int GRID = 256;
constexpr int BLK  = 512;
constexpr int NT   = GRID * BLK;   // 131072 threads >= N
constexpr int MAXW = 1600;         // LDS bitmask words (N/64 = 1563)

// ---------------- tiny init: slot packing + barrier counter ----------------
__global__ void init_kernel(const int* __restrict__ post, const int* __restrict__ rc,
                            int* __restrict__ slot, int* __restrict__ ctr, int E) {
    int i = blockIdx.x * blockDim.x + threadIdx.x;
    if (i < E) slot[i] = post[i] * RR + rc[i];
    if (i == 0) *ctr = 0;
}

__device__ __forceinline__ void grid_barrier(int* ctr, int target) {
    __syncthreads();   // compiler emits s_waitcnt vmcnt(0) before s_barrier:
                       // every wave's atomics/stores are drained before arrival
    if (threadIdx.x == 0) {
        __hip_atomic_fetch_add(ctr, 1, __ATOMIC_RELAXED, __HIP_MEMORY_SCOPE_AGENT);
        while (__hip_atomic_load(ctr, __ATOMIC_RELAXED, __HIP_MEMORY_SCOPE_AGENT) < target)
            __builtin_amdgcn_s_sleep(4);
    }
    __syncthreads();
}

__global__ __launch_bounds__(BLK, 2) void persistent_kernel(
    const float4* __restrict__ x4p,           // [T][N] float4 (R=4)
    float* __restrict__ out,                  // [T][N]
    float* __restrict__ rec,                  // [4N] rec_in accumulator
    unsigned long long* __restrict__ mask,    // spike bitmask (global)
    int* __restrict__ ctr,
    const int4* __restrict__ pre4, const int4* __restrict__ slot4,
    const float4* __restrict__ w4,
    const float* __restrict__ v0p, const float* __restrict__ vthp,
    const float* __restrict__ vrstp, const float* __restrict__ trfp,
    const float* __restrict__ decp, const float* __restrict__ cfp,
    const float* __restrict__ elp,
    const float2* __restrict__ aap, const float2* __restrict__ adp,
    const float* __restrict__ syn_d, const float* __restrict__ psc_i,
    int N, int T, int E) {
    __shared__ unsigned long long smask[MAXW];
    const int tid = blockIdx.x * BLK + threadIdx.x;
    const bool own = tid < N;
    const int E4 = E >> 2;
    const int NW = (N + 63) >> 6;             // bitmask words in use

    const float sd0 = syn_d[0], sd1 = syn_d[1], sd2 = syn_d[2], sd3 = syn_d[3];
    const float pi0 = psc_i[0], pi1 = psc_i[1], pi2 = psc_i[2], pi3 = psc_i[3];

    // per-neuron params + state: registers for the whole run
    float v = 0.f, r = 0.f, z = 0.f, a0 = 0.f, a1 = 0.f;
    float pc0 = 0.f, pc1 = 0.f, pc2 = 0.f, pc3 = 0.f;
    float pr0 = 0.f, pr1 = 0.f, pr2 = 0.f, pr3 = 0.f;
    float vth = 1.f, vrst = 0.f, trf = 0.f, dec = 0.f, cf = 0.f, el = 0.f;
    float aa0 = 0.f, aa1 = 0.f, ad0 = 0.f, ad1 = 0.f;
    if (own) {
        v = v0p[tid]; vth = vthp[tid]; vrst = vrstp[tid]; trf = trfp[tid];
        dec = decp[tid]; cf = cfp[tid]; el = elp[tid];
        float2 aa = aap[tid]; aa0 = aa.x; aa1 = aa.y;
        float2 ad = adp[tid]; ad0 = ad.x; ad1 = ad.y;
        // zero my rec slots at the coherence point (agent scope, bypass L1/L2)
        float* rp = rec + (size_t)tid * 4;
        __hip_atomic_store(rp + 0, 0.f, __ATOMIC_RELAXED, __HIP_MEMORY_SCOPE_AGENT);
        __hip_atomic_store(rp + 1, 0.f, __ATOMIC_RELAXED, __HIP_MEMORY_SCOPE_AGENT);
        __hip_atomic_store(rp + 2, 0.f, __ATOMIC_RELAXED, __HIP_MEMORY_SCOPE_AGENT);
        __hip_atomic_store(rp + 3, 0.f, __ATOMIC_RELAXED, __HIP_MEMORY_SCOPE_AGENT);
    }

    int bk = 0;
    for (int t = 0; t < T; ++t) {
        // prefetch this step's external input (HBM latency hidden by scatter)
        float4 x4 = make_float4(0.f, 0.f, 0.f, 0.f);
        if (own) x4 = x4p[(size_t)t * N + tid];

        if (t > 0) {   // z == 0 at t == 0: nothing to scatter
            // stage spike bitmask into LDS (agent loads: coherent vs other XCDs)
            for (int i2 = threadIdx.x; i2 < NW; i2 += BLK)
                smask[i2] = __hip_atomic_load(&mask[i2], __ATOMIC_RELAXED,
                                              __HIP_MEMORY_SCOPE_AGENT);
            __syncthreads();
            for (int p = tid; p < E4; p += NT) {
                int4 pp = pre4[p];
                bool b0 = (smask[pp.x >> 6] >> (pp.x & 63)) & 1ull;
                bool b1 = (smask[pp.y >> 6] >> (pp.y & 63)) & 1ull;
                bool b2 = (smask[pp.z >> 6] >> (pp.z & 63)) & 1ull;
                bool b3 = (smask[pp.w >> 6] >> (pp.w & 63)) & 1ull;
                if (b0 | b1 | b2 | b3) {
                    int4 ss = slot4[p];
                    float4 ww = w4[p];
                    if (b0) atomicAdd(rec + ss.x, ww.x);
                    if (b1) atomicAdd(rec + ss.y, ww.y);
                    if (b2) atomicAdd(rec + ss.z, ww.z);
                    if (b3) atomicAdd(rec + ss.w, ww.w);
                }
            }
            int rem = E & 3;
            if (tid < rem) {
                int e = (E & ~3) + tid;
                int p = ((const int*)pre4)[e];
                if ((mask[p >> 6] >> (p & 63)) & 1ull)
                    atomicAdd(rec + ((const int*)slot4)[e], ((const float*)w4)[e]);
            }
            grid_barrier(ctr, ++bk * GRID);
        }

        // ---- in-register neuron update ----
        float nz = 0.f;
        if (own) {
            float* rp = rec + (size_t)tid * 4;
            float ri0 = __hip_atomic_load(rp + 0, __ATOMIC_RELAXED, __HIP_MEMORY_SCOPE_AGENT);
            float ri1 = __hip_atomic_load(rp + 1, __ATOMIC_RELAXED, __HIP_MEMORY_SCOPE_AGENT);
            float ri2 = __hip_atomic_load(rp + 2, __ATOMIC_RELAXED, __HIP_MEMORY_SCOPE_AGENT);
            float ri3 = __hip_atomic_load(rp + 3, __ATOMIC_RELAXED, __HIP_MEMORY_SCOPE_AGENT);
            // re-zero at the coherence point for the next scatter
            __hip_atomic_store(rp + 0, 0.f, __ATOMIC_RELAXED, __HIP_MEMORY_SCOPE_AGENT);
            __hip_atomic_store(rp + 1, 0.f, __ATOMIC_RELAXED, __HIP_MEMORY_SCOPE_AGENT);
            __hip_atomic_store(rp + 2, 0.f, __ATOMIC_RELAXED, __HIP_MEMORY_SCOPE_AGENT);
            __hip_atomic_store(rp + 3, 0.f, __ATOMIC_RELAXED, __HIP_MEMORY_SCOPE_AGENT);

            float in0 = ri0 + x4.x, in1 = ri1 + x4.y, in2 = ri2 + x4.z, in3 = ri3 + x4.w;
            float npr0 = pr0 * sd0 + in0 * pi0;
            float npr1 = pr1 * sd1 + in1 * pi1;
            float npr2 = pr2 * sd2 + in2 * pi2;
            float npr3 = pr3 * sd3 + in3 * pi3;
            float npc0 = pc0 * sd0 + sd0 * pr0;   // OLD psc_rise, DT=1
            float npc1 = pc1 * sd1 + sd1 * pr1;
            float npc2 = pc2 * sd2 + sd2 * pr2;
            float npc3 = pc3 * sd3 + sd3 * pr3;
            float ic = npc0 + npc1 + npc2 + npc3 + a0 + a1;   // new psc + OLD asc
            a0 = ad0 * a0 + z * aa0;
            a1 = ad1 * a1 + z * aa1;
            float vv  = dec * v + cf * (ic + el) + z * (vrst - vth);
            float vsc = (vv - vth) / vth;
            nz = (vsc > 0.f) ? 1.f : 0.f;
            if (r > 0.f) nz = 0.f;                 // refractory (OLD r)
            r = fmaxf(r - 1.f + nz * trf, 0.f);
            v = vv; z = nz;
            pr0 = npr0; pr1 = npr1; pr2 = npr2; pr3 = npr3;
            pc0 = npc0; pc1 = npc1; pc2 = npc2; pc3 = npc3;
            out[(size_t)t * N + tid] = nz;
        }
        unsigned long long bal = __ballot(nz > 0.f);
        if ((threadIdx.x & 63) == 0 && own)
            __hip_atomic_store(&mask[tid >> 6], bal, __ATOMIC_RELAXED,
                               __HIP_MEMORY_SCOPE_AGENT);
        if (t + 1 < T) grid_barrier(ctr, ++bk * GRID);
    }
}

extern "C" void kernel_launch(void* const* d_in, const int* in_sizes, int n_in,
                              void* d_out, int out_size, void* d_ws, size_t ws_size,
                              hipStream_t stream) {
    const float* w_rec = (const float*)d_in[0];
    const float* x_ext = (const float*)d_in[1];
    const float* v0    = (const float*)d_in[2];
    const float* v_th  = (const float*)d_in[3];
    const float* v_rst = (const float*)d_in[4];
    const float* t_rf  = (const float*)d_in[5];
    const float* decay = (const float*)d_in[6];
    const float* curf  = (const float*)d_in[7];
    const float* e_l   = (const float*)d_in[8];
    const float* aamps = (const float*)d_in[9];
    const float* adec  = (const float*)d_in[10];
    const float* syn_d = (const float*)d_in[11];
    const float* psc_i = (const float*)d_in[12];
    const int*   pre   = (const int*)d_in[13];
    const int*   post  = (const int*)d_in[14];
    const int*   rc    = (const int*)d_in[15];
    float* out = (float*)d_out;

    int E = in_sizes[0];
    int N = in_sizes[2];            // B == 1
    int T = in_sizes[1] / (N * RR);

    // -------- workspace layout (16B-aligned chunks) --------
    char* wp = (char*)d_ws;
    auto alloc = [&](size_t bytes) { char* p = wp; wp += (bytes + 15) & ~15ull; return p; };
    int*   slot = (int*)alloc((size_t)E * 4);
    float* rec  = (float*)alloc((size_t)N * 16);
    unsigned long long* mask = (unsigned long long*)alloc((size_t)MAXW * 8);
    int*   ctr  = (int*)alloc(64);

    init_kernel<<<(E + 255) / 256, 256, 0, stream>>>(post, rc, slot, ctr, E);

    const float4* x4p   = (const float4*)x_ext;
    const int4*   pre4  = (const int4*)pre;
    const int4*   slot4 = (const int4*)slot;
    const float4* w4    = (const float4*)w_rec;
    const float2* aap   = (const float2*)aamps;
    const float2* adp   = (const float2*)adec;

    void* args[] = {
        (void*)&x4p, (void*)&out, (void*)&rec, (void*)&mask, (void*)&ctr,
        (void*)&pre4, (void*)&slot4, (void*)&w4,
        (void*)&v0, (void*)&v_th, (void*)&v_rst, (void*)&t_rf,
        (void*)&decay, (void*)&curf, (void*)&e_l,
        (void*)&aap, (void*)&adp, (void*)&syn_d, (void*)&psc_i,
        (void*)&N, (void*)&T, (void*)&E,
    };
    hipLaunchCooperativeKernel((const void*)persistent_kernel,
                               dim3(GRID), dim3(BLK), args, 0, stream);
}

// Round 8
// 1040.598 us; speedup vs baseline: 1.4405x; 1.4405x over previous
//
#include <hip/hip_runtime.h>

// Billeh column GLIF forward — ONE kernel per step, replicated-update fusion.
// Synapses counting-sorted by pre-bucket (256 neurons). Launch t, block
// (bucket,rep): all K replicas redundantly compute the bucket's neuron update
// (reading double-buffered state + rec[t%3], all read-only this launch);
// rep 0 alone writes new state/out and zeroes rec[(t+2)%3]; then every
// replica scatters a disjoint 1/K slice of the bucket's synapses, gated by
// block-local LDS z, into rec[(t+1)%3]. All cross-step deps cross a kernel
// boundary; within a launch no buffer is both read and written by different
// blocks.

constexpr int RR = 4;
constexpr int BK = 256;    // neurons per bucket / block
constexpr int K  = 5;      // update replicas per bucket
constexpr int CH = 4096;   // synapses per hist/place chunk
constexpr int NBMAX = 512; // scan width (NB = 391 fits)

// ---------------- init: state + params + rec + counters ----------------
__global__ void init_kernel(const float* __restrict__ v0,
                            const float* __restrict__ v_th, const float* __restrict__ v_rst,
                            const float* __restrict__ t_rf, const float* __restrict__ decay,
                            const float* __restrict__ curf, const float* __restrict__ e_l,
                            const float2* __restrict__ aamps, const float2* __restrict__ adec,
                            float4* __restrict__ rec0, float4* __restrict__ rec1,
                            float4* __restrict__ rec2,
                            float4* __restrict__ psc0, float4* __restrict__ prise0,
                            float4* __restrict__ stA0, float* __restrict__ z0,
                            float4* __restrict__ p0, float4* __restrict__ p1,
                            float2* __restrict__ p2, int* __restrict__ cnt,
                            int N, int NB) {
    int i = blockIdx.x * blockDim.x + threadIdx.x;
    if (i < N) {
        float4 z4 = make_float4(0.f, 0.f, 0.f, 0.f);
        rec0[i] = z4; rec1[i] = z4; rec2[i] = z4;
        psc0[i] = z4; prise0[i] = z4;
        stA0[i] = make_float4(v0[i], 0.f, 0.f, 0.f);   // v, r, a0, a1
        z0[i] = 0.f;
        p0[i] = make_float4(v_th[i], v_rst[i], t_rf[i], decay[i]);
        float2 aa = aamps[i];
        p1[i] = make_float4(curf[i], e_l[i], aa.x, aa.y);
        p2[i] = adec[i];
    }
    if (i < NB) cnt[i] = 0;
}

// ---------------- bucket sort pass 1: histogram ----------------
__global__ void hist_kernel(const int* __restrict__ pre, int* __restrict__ cnt,
                            int E, int NB) {
    __shared__ int h[NBMAX];
    for (int b = threadIdx.x; b < NB; b += BK) h[b] = 0;
    __syncthreads();
    int base = blockIdx.x * CH;
#pragma unroll
    for (int j = 0; j < CH / BK; j++) {
        int idx = base + j * BK + threadIdx.x;
        if (idx < E) atomicAdd(&h[pre[idx] >> 8], 1);
    }
    __syncthreads();
    for (int b = threadIdx.x; b < NB; b += BK)
        if (h[b]) atomicAdd(&cnt[b], h[b]);
}

// ---------------- bucket sort pass 2: scan (NB <= 512) ----------------
__global__ void scan_kernel(const int* __restrict__ cnt, int* __restrict__ offs,
                            int* __restrict__ cursor, int NB, int E) {
    __shared__ int s[NBMAX];
    int t = threadIdx.x;
    int v = (t < NB) ? cnt[t] : 0;
    s[t] = v; __syncthreads();
    for (int off = 1; off < NBMAX; off <<= 1) {
        int x = (t >= off) ? s[t - off] : 0;
        __syncthreads();
        s[t] += x;
        __syncthreads();
    }
    if (t < NB) {
        int excl = s[t] - v;
        offs[t] = excl;
        cursor[t] = excl;
    }
    if (t == 0) offs[NB] = E;
}

// ---------------- bucket sort pass 3: placement ----------------
__global__ void place_kernel(const int* __restrict__ pre, const int* __restrict__ post,
                             const int* __restrict__ rc, const float* __restrict__ w,
                             int* __restrict__ cursor, int2* __restrict__ syn,
                             int E, int NB) {
    __shared__ int h[NBMAX];
    __shared__ int hbase[NBMAX];
    for (int b = threadIdx.x; b < NB; b += BK) h[b] = 0;
    __syncthreads();
    int base = blockIdx.x * CH;
#pragma unroll
    for (int j = 0; j < CH / BK; j++) {
        int idx = base + j * BK + threadIdx.x;
        if (idx < E) atomicAdd(&h[pre[idx] >> 8], 1);
    }
    __syncthreads();
    for (int b = threadIdx.x; b < NB; b += BK) {
        int c = h[b];
        if (c) hbase[b] = atomicAdd(&cursor[b], c);
        h[b] = 0;
    }
    __syncthreads();
#pragma unroll
    for (int j = 0; j < CH / BK; j++) {
        int idx = base + j * BK + threadIdx.x;
        if (idx < E) {
            int p = pre[idx];
            int bk = p >> 8;
            int pos = hbase[bk] + atomicAdd(&h[bk], 1);
            int slot = post[idx] * RR + rc[idx];
            syn[pos] = make_int2((slot << 8) | (p & 255), __float_as_int(w[idx]));
        }
    }
}

// ---------------- per-step fused replicated-update + sliced scatter --------
__global__ __launch_bounds__(BK) void step_kernel(
    const float4* __restrict__ x_t, float* __restrict__ out_t,
    const float4* __restrict__ rec_r,     // rec[t%3]: read-only this launch
    float* __restrict__ rec_w,            // rec[(t+1)%3]: scatter target
    float4* __restrict__ rec_z,           // rec[(t+2)%3]: zeroed by rep 0
    const int2* __restrict__ syn, const int* __restrict__ offs,
    const float4* __restrict__ p0, const float4* __restrict__ p1,
    const float2* __restrict__ p2,
    const float* __restrict__ syn_d, const float* __restrict__ psc_i,
    const float4* __restrict__ psc_r, const float4* __restrict__ prise_r,
    const float4* __restrict__ stA_r, const float* __restrict__ z_r,
    float4* __restrict__ psc_w, float4* __restrict__ prise_w,
    float4* __restrict__ stA_w, float* __restrict__ z_w,
    int N, int NB, int do_scatter) {
    __shared__ float zl[BK];
    const int bucket = blockIdx.x % NB;
    const int rep    = blockIdx.x / NB;
    const int tid = threadIdx.x;
    const int n = bucket * BK + tid;

    float nz = 0.f;
    if (n < N) {
        const float sd0 = syn_d[0], sd1 = syn_d[1], sd2 = syn_d[2], sd3 = syn_d[3];
        const float pi0 = psc_i[0], pi1 = psc_i[1], pi2 = psc_i[2], pi3 = psc_i[3];
        float4 ri = rec_r[n];
        float4 x4 = x_t[n];
        float4 pr = prise_r[n];
        float4 pc = psc_r[n];
        float4 sa = stA_r[n];                        // v, r, a0, a1
        float z = z_r[n];
        float4 P0 = p0[n];                           // vth, vrst, tref, decay
        float4 P1 = p1[n];                           // cf, el, aa0, aa1
        float2 ad = p2[n];

        float in0 = ri.x + x4.x, in1 = ri.y + x4.y, in2 = ri.z + x4.z, in3 = ri.w + x4.w;
        float npr0 = pr.x * sd0 + in0 * pi0;
        float npr1 = pr.y * sd1 + in1 * pi1;
        float npr2 = pr.z * sd2 + in2 * pi2;
        float npr3 = pr.w * sd3 + in3 * pi3;
        float npc0 = pc.x * sd0 + sd0 * pr.x;        // OLD psc_rise, DT=1
        float npc1 = pc.y * sd1 + sd1 * pr.y;
        float npc2 = pc.z * sd2 + sd2 * pr.z;
        float npc3 = pc.w * sd3 + sd3 * pr.w;
        float ic = npc0 + npc1 + npc2 + npc3 + sa.z + sa.w;   // new psc + OLD asc
        float a0 = ad.x * sa.z + z * P1.z;
        float a1 = ad.y * sa.w + z * P1.w;
        float vth = P0.x;
        float vv  = P0.w * sa.x + P1.x * (ic + P1.y) + z * (P0.y - vth);
        float vsc = (vv - vth) / vth;
        nz = (vsc > 0.f) ? 1.f : 0.f;
        if (sa.y > 0.f) nz = 0.f;                    // refractory (OLD r)

        if (rep == 0) {
            float nr = fmaxf(sa.y - 1.f + nz * P0.z, 0.f);
            prise_w[n] = make_float4(npr0, npr1, npr2, npr3);
            psc_w[n]   = make_float4(npc0, npc1, npc2, npc3);
            stA_w[n]   = make_float4(vv, nr, a0, a1);
            z_w[n]     = nz;
            out_t[n]   = nz;
            rec_z[n]   = make_float4(0.f, 0.f, 0.f, 0.f);  // recycle for t+2
        }
    }
    zl[tid] = nz;
    __syncthreads();

    if (do_scatter) {
        int s0 = offs[bucket], s1 = offs[bucket + 1];
        int len = s1 - s0;
        int chunk = (len + K - 1) / K;
        int a = s0 + rep * chunk;
        int b2 = a + chunk; if (b2 > s1) b2 = s1;
        for (int i = a + tid; i < b2; i += BK) {
            int2 e = syn[i];
            if (zl[e.x & 255] != 0.f)
                atomicAdd(rec_w + (e.x >> 8), __int_as_float(e.y));
        }
    }
}

extern "C" void kernel_launch(void* const* d_in, const int* in_sizes, int n_in,
                              void* d_out, int out_size, void* d_ws, size_t ws_size,
                              hipStream_t stream) {
    const float* w_rec = (const float*)d_in[0];
    const float* x_ext = (const float*)d_in[1];
    const float* v0    = (const float*)d_in[2];
    const float* v_th  = (const float*)d_in[3];
    const float* v_rst = (const float*)d_in[4];
    const float* t_rf  = (const float*)d_in[5];
    const float* decay = (const float*)d_in[6];
    const float* curf  = (const float*)d_in[7];
    const float* e_l   = (const float*)d_in[8];
    const float* aamps = (const float*)d_in[9];
    const float* adec  = (const float*)d_in[10];
    const float* syn_d = (const float*)d_in[11];
    const float* psc_i = (const float*)d_in[12];
    const int*   pre   = (const int*)d_in[13];
    const int*   post  = (const int*)d_in[14];
    const int*   rc    = (const int*)d_in[15];
    float* out = (float*)d_out;

    const int E  = in_sizes[0];
    const int N  = in_sizes[2];            // B == 1
    const int T  = in_sizes[1] / (N * RR);
    const int NB = (N + BK - 1) / BK;      // buckets (391)

    // -------- workspace layout (16B-aligned chunks) --------
    char* wp = (char*)d_ws;
    auto alloc = [&](size_t bytes) { char* p = wp; wp += (bytes + 15) & ~15ull; return p; };
    float4* rec[3];
    for (int i = 0; i < 3; i++) rec[i] = (float4*)alloc((size_t)N * 16);
    float4* psc[2];   for (int i = 0; i < 2; i++) psc[i]   = (float4*)alloc((size_t)N * 16);
    float4* prise[2]; for (int i = 0; i < 2; i++) prise[i] = (float4*)alloc((size_t)N * 16);
    float4* stA[2];   for (int i = 0; i < 2; i++) stA[i]   = (float4*)alloc((size_t)N * 16);
    float*  zarr[2];  for (int i = 0; i < 2; i++) zarr[i]  = (float*)alloc((size_t)N * 4);
    float4* p0 = (float4*)alloc((size_t)N * 16);
    float4* p1 = (float4*)alloc((size_t)N * 16);
    float2* p2 = (float2*)alloc((size_t)N * 8);
    int* cnt    = (int*)alloc((size_t)NB * 4);
    int* offs   = (int*)alloc((size_t)(NB + 1) * 4);
    int* cursor = (int*)alloc((size_t)NB * 4);
    int2* syn   = (int2*)alloc((size_t)E * 8);

    const int NCH = (E + CH - 1) / CH;

    init_kernel<<<(N + BK - 1) / BK, BK, 0, stream>>>(
        v0, v_th, v_rst, t_rf, decay, curf, e_l,
        (const float2*)aamps, (const float2*)adec,
        rec[0], rec[1], rec[2], psc[0], prise[0], stA[0], zarr[0],
        p0, p1, p2, cnt, N, NB);
    hist_kernel<<<NCH, BK, 0, stream>>>(pre, cnt, E, NB);
    scan_kernel<<<1, NBMAX, 0, stream>>>(cnt, offs, cursor, NB, E);
    place_kernel<<<NCH, BK, 0, stream>>>(pre, post, rc, w_rec, cursor, syn, E, NB);

    for (int t = 0; t < T; t++) {
        int rr0 = t % 3, rw = (t + 1) % 3, rz = (t + 2) % 3;
        int sr = t & 1, sw2 = (t + 1) & 1;
        step_kernel<<<NB * K, BK, 0, stream>>>(
            (const float4*)(x_ext + (size_t)t * N * RR),
            out + (size_t)t * N,
            rec[rr0], (float*)rec[rw], rec[rz],
            syn, offs, p0, p1, p2, syn_d, psc_i,
            psc[sr], prise[sr], stA[sr], zarr[sr],
            psc[sw2], prise[sw2], stA[sw2], zarr[sw2],
            N, NB, (t + 1 < T) ? 1 : 0);
    }
}